// Round 6
// baseline (164.134 us; speedup 1.0000x reference)
//
#include <hip/hip_runtime.h>

// Single-query cross-attention, algebraically collapsed:
//   scores[h,l] = (scale*Wk_h^T q_h) . x[l]      (k-bias cancels in softmax)
//   out_attn[h] = Wv_h @ (sum_l softmax_w[l] * x[l]) + bv_h
// => one streaming pass over x (64 MB), memory-bound.
// R5: per-row reduce rebuilt — 4x4 lane-group transpose (3 shfl) + 4-stage
// same-residue butterfly + ONE exp/row + rotated-head accumulators.
// qkb dropped (exact softmax cancellation). launch_bounds(256,8) pins
// 8 waves/EU. NSLOT=16.

#define DIM   512
#define NH    4
#define HDIM  128
#define SCALE 0.08838834764831845f  // 1/sqrt(128)

#define NB              2048
#define ROWS_PER_BLOCK  16
#define ROWS_PER_WAVE   4
#define NSLOT           16

// ws layout (float offsets). Total 35904 floats ~ 140 KB.
#define WS_Q     0      // 512
#define WS_QKS   512    // NH*DIM = 2048 (scale * Wk_h^T q_h), atomic-accumulated
#define WS_ATTN  2560   // 512
#define WS_S     3072   // NSLOT*NH = 64 softmax denominators
#define WS_XA    3136   // NSLOT*NH*DIM = 32768 weighted x-sum slots

// 128 blocks: one wave per output d; also zeros all atomic accumulators.
__global__ __launch_bounds__(256)
void k_qproj(const float* __restrict__ x, const float* __restrict__ ipw,
             const float* __restrict__ ipb, float* __restrict__ ws) {
  const int g = blockIdx.x * 256 + threadIdx.x;  // 0..32767
  ws[WS_XA + g] = 0.f;                            // exactly NSLOT*NH*DIM
  if (g < NSLOT * NH) ws[WS_S + g]   = 0.f;
  if (g < NH * DIM)   ws[WS_QKS + g] = 0.f;

  const int wave = threadIdx.x >> 6, lane = threadIdx.x & 63;
  const int d = blockIdx.x * 4 + wave;  // 0..511
  const float4 xa = *(const float4*)(x + lane * 8);
  const float4 xb = *(const float4*)(x + lane * 8 + 4);
  const float* wr = ipw + (size_t)d * DIM + lane * 8;
  const float4 wa = *(const float4*)wr;
  const float4 wb = *(const float4*)(wr + 4);
  float acc = wa.x*xa.x + wa.y*xa.y + wa.z*xa.z + wa.w*xa.w
            + wb.x*xb.x + wb.y*xb.y + wb.z*xb.z + wb.w*xb.w;
  #pragma unroll
  for (int off = 32; off; off >>= 1) acc += __shfl_xor(acc, off, 64);
  if (lane == 0) ws[WS_Q + d] = acc + ipb[d];
}

// 64 blocks x 4 waves = 256 waves: wave = (64-output chunk o) x (16-wide hd eighth).
// Coalesced 256B row-chunk loads; 8 atomicAdds per output address.
__global__ __launch_bounds__(256)
void k_qk(const float* __restrict__ ipw, float* __restrict__ ws) {
  const int wave = threadIdx.x >> 6, lane = threadIdx.x & 63;
  const int W  = blockIdx.x * 4 + wave;  // 0..255
  const int o  = W & 31;                 // output chunk (64 outputs)
  const int he = W >> 5;                 // hd eighth (16 rows)
  const int h  = o >> 3;
  const int col = o * 64 + lane;         // flat out index = h*512 + dp
  const int dp  = col & 511;
  const float* q = ws + WS_Q + h * HDIM + he * 16;
  const float* wbase = ipw + (size_t)(DIM + h * HDIM + he * 16) * DIM + dp;
  float acc = 0.f;
  #pragma unroll
  for (int i = 0; i < 16; ++i)
    acc += q[i] * wbase[(size_t)i * DIM];
  atomicAdd(ws + WS_QKS + col, acc * SCALE);
}

// Main pass: stream x; per row: 4 partial dots -> 4x4 lane-group transpose ->
// 4-stage butterfly -> one exp -> rotated-head accumulate. LDS 2-buffer
// combine; striped atomicAdd into xA/S slots.
__global__ __launch_bounds__(256, 8)
void k_main(const float* __restrict__ x, float* __restrict__ ws) {
  const int wave = threadIdx.x >> 6, lane = threadIdx.x & 63;
  const bool b1 = lane & 1, b2 = lane & 2;
  const int row0 = blockIdx.x * ROWS_PER_BLOCK + wave * ROWS_PER_WAVE;

  float qk[NH][8];
  #pragma unroll
  for (int h = 0; h < NH; ++h) {
    const float4 a = *(const float4*)(ws + WS_QKS + h * DIM + lane * 8);
    const float4 b = *(const float4*)(ws + WS_QKS + h * DIM + lane * 8 + 4);
    qk[h][0]=a.x; qk[h][1]=a.y; qk[h][2]=a.z; qk[h][3]=a.w;
    qk[h][4]=b.x; qk[h][5]=b.y; qk[h][6]=b.z; qk[h][7]=b.w;
  }

  float s = 0.f;          // denominator of head (lane&3), identical across its 16 lanes
  float xacc[NH][8];      // xacc[i] accumulates head (lane&3)^i
  #pragma unroll
  for (int i = 0; i < NH; ++i)
    #pragma unroll
    for (int j = 0; j < 8; ++j) xacc[i][j] = 0.f;

  const float* xp = x + (size_t)row0 * DIM + lane * 8;
  #pragma unroll
  for (int r = 0; r < ROWS_PER_WAVE; ++r) {
    const float* rp = xp + (size_t)r * DIM;
    const float4 a = *(const float4*)rp;
    const float4 b = *(const float4*)(rp + 4);
    const float xr[8] = {a.x,a.y,a.z,a.w,b.x,b.y,b.z,b.w};
    float d0=0.f,d1=0.f,d2=0.f,d3=0.f;
    #pragma unroll
    for (int j = 0; j < 8; ++j) {
      d0 += qk[0][j]*xr[j]; d1 += qk[1][j]*xr[j];
      d2 += qk[2][j]*xr[j]; d3 += qk[3][j]*xr[j];
    }
    // tier 1: 4x4 transpose-reduce within 4-lane groups -> lane holds head (l&3) group partial
    const float x01 = b1 ? d0 : d1;
    const float x23 = b1 ? d2 : d3;
    const float A = (b1 ? d1 : d0) + __shfl_xor(x01, 1, 64);
    const float B = (b1 ? d3 : d2) + __shfl_xor(x23, 1, 64);
    const float y = b2 ? A : B;
    float v = (b2 ? B : A) + __shfl_xor(y, 2, 64);
    // tier 2: butterfly over same-residue lanes -> full score of head (l&3)
    v += __shfl_xor(v, 4, 64);
    v += __shfl_xor(v, 8, 64);
    v += __shfl_xor(v, 16, 64);
    v += __shfl_xor(v, 32, 64);
    // one exp per row (per lane: its head)
    const float w0 = __expf(v);
    const float w1 = __shfl_xor(w0, 1, 64);   // head (l&3)^1
    const float w2 = __shfl_xor(w0, 2, 64);   // head (l&3)^2
    const float w3 = __shfl_xor(w0, 3, 64);   // head (l&3)^3
    s += w0;
    #pragma unroll
    for (int j = 0; j < 8; ++j) {
      xacc[0][j] += w0 * xr[j];
      xacc[1][j] += w1 * xr[j];
      xacc[2][j] += w2 * xr[j];
      xacc[3][j] += w3 * xr[j];
    }
  }

  // 2-buffer combine: waves 2,3 store; waves 0,1 add. 16.1 KB LDS.
  __shared__ float lds_xa[2][NH * DIM];
  __shared__ float lds_s[4][NH];
  const int hbase = lane & 3;
  if (wave >= 2) {
    #pragma unroll
    for (int i = 0; i < NH; ++i)
      #pragma unroll
      for (int j = 0; j < 8; ++j)
        lds_xa[wave - 2][((hbase ^ i) << 9) + lane * 8 + j] = xacc[i][j];
  }
  if (lane < NH) lds_s[wave][lane] = s;   // lane h holds head h's denominator
  __syncthreads();
  if (wave < 2) {
    #pragma unroll
    for (int i = 0; i < NH; ++i)
      #pragma unroll
      for (int j = 0; j < 8; ++j)
        lds_xa[wave][((hbase ^ i) << 9) + lane * 8 + j] += xacc[i][j];
  }
  __syncthreads();

  const int slot = blockIdx.x & (NSLOT - 1);
  if (threadIdx.x < NH) {
    const int h = threadIdx.x;
    atomicAdd(ws + WS_S + slot * NH + h,
              lds_s[0][h] + lds_s[1][h] + lds_s[2][h] + lds_s[3][h]);
  }
  #pragma unroll
  for (int j = 0; j < 8; ++j) {
    const int p = threadIdx.x + 256 * j;  // 0..2047, stride-1 across lanes
    atomicAdd(ws + WS_XA + slot * (NH * DIM) + p, lds_xa[0][p] + lds_xa[1][p]);
  }
}

// 128 blocks: one wave per output c. Sums the 16 xA/S slots inline.
__global__ __launch_bounds__(256)
void k_vproj(const float* __restrict__ ipw, const float* __restrict__ ipb,
             float* __restrict__ ws) {
  const int wave = threadIdx.x >> 6, lane = threadIdx.x & 63;
  const int c = blockIdx.x * 4 + wave;  // 0..511
  const int h = c >> 7;
  float xs[8] = {0.f,0.f,0.f,0.f,0.f,0.f,0.f,0.f};
  #pragma unroll
  for (int sl = 0; sl < NSLOT; ++sl) {
    const float* xv = ws + WS_XA + sl * (NH * DIM) + h * DIM + lane * 8;
    const float4 a = *(const float4*)xv;
    const float4 b = *(const float4*)(xv + 4);
    xs[0]+=a.x; xs[1]+=a.y; xs[2]+=a.z; xs[3]+=a.w;
    xs[4]+=b.x; xs[5]+=b.y; xs[6]+=b.z; xs[7]+=b.w;
  }
  float S = 0.f;
  #pragma unroll
  for (int sl = 0; sl < NSLOT; ++sl) S += ws[WS_S + sl * NH + h];

  const float* wr = ipw + (size_t)(2 * DIM + c) * DIM + lane * 8;
  const float4 wa = *(const float4*)wr;
  const float4 wb = *(const float4*)(wr + 4);
  float acc = wa.x*xs[0] + wa.y*xs[1] + wa.z*xs[2] + wa.w*xs[3]
            + wb.x*xs[4] + wb.y*xs[5] + wb.z*xs[6] + wb.w*xs[7];
  #pragma unroll
  for (int off = 32; off; off >>= 1) acc += __shfl_xor(acc, off, 64);
  if (lane == 0)
    ws[WS_ATTN + c] = acc / S + ipb[2 * DIM + c];
}

// 128 blocks: one wave per output i.
__global__ __launch_bounds__(256)
void k_oproj(const float* __restrict__ opw, const float* __restrict__ opb,
             const float* __restrict__ ws, float* __restrict__ out) {
  const int wave = threadIdx.x >> 6, lane = threadIdx.x & 63;
  const int i = blockIdx.x * 4 + wave;  // 0..511
  const float4 aa = *(const float4*)(ws + WS_ATTN + lane * 8);
  const float4 ab = *(const float4*)(ws + WS_ATTN + lane * 8 + 4);
  const float* wr = opw + (size_t)i * DIM + lane * 8;
  const float4 wa = *(const float4*)wr;
  const float4 wb = *(const float4*)(wr + 4);
  float acc = wa.x*aa.x + wa.y*aa.y + wa.z*aa.z + wa.w*aa.w
            + wb.x*ab.x + wb.y*ab.y + wb.z*ab.z + wb.w*ab.w;
  #pragma unroll
  for (int off = 32; off; off >>= 1) acc += __shfl_xor(acc, off, 64);
  if (lane == 0) out[i] = acc + opb[i];
}

extern "C" void kernel_launch(void* const* d_in, const int* in_sizes, int n_in,
                              void* d_out, int out_size, void* d_ws, size_t ws_size,
                              hipStream_t stream) {
  const float* x   = (const float*)d_in[0];
  const float* ipw = (const float*)d_in[1];
  const float* ipb = (const float*)d_in[2];
  const float* opw = (const float*)d_in[3];
  const float* opb = (const float*)d_in[4];
  float* out = (float*)d_out;
  float* ws  = (float*)d_ws;

  k_qproj<<<128, 256, 0, stream>>>(x, ipw, ipb, ws);
  k_qk   <<<64,  256, 0, stream>>>(ipw, ws);
  k_main <<<NB,  256, 0, stream>>>(x, ws);
  k_vproj<<<128, 256, 0, stream>>>(ipw, ipb, ws);
  k_oproj<<<128, 256, 0, stream>>>(opw, opb, ws, out);
}

// Round 8
// 125.229 us; speedup vs baseline: 1.3107x; 1.3107x over previous
//
#include <hip/hip_runtime.h>

// Single-query cross-attention, algebraically collapsed:
//   scores[h,l] = (scale*Wk_h^T q_h) . x[l]      (k-bias cancels in softmax)
//   out_attn[h] = Wv_h @ (sum_l softmax_w[l] * x[l]) + bv_h
// => one streaming pass over x (64 MB), memory-bound.
// R7: fix R6 spill — launch_bounds(256,8) capped VGPR at 64 but live state
// needs ~70-90 -> 54 floats/thread scratch spill (WRITE_SIZE 114 MB, VALUBusy
// 6.5%). Relax to (256,4): 128-VGPR cap, no spill, 16 waves/CU.

#define DIM   512
#define NH    4
#define HDIM  128
#define SCALE 0.08838834764831845f  // 1/sqrt(128)

#define NB              2048
#define ROWS_PER_BLOCK  16
#define ROWS_PER_WAVE   4
#define NSLOT           16

// ws layout (float offsets). Total 35904 floats ~ 140 KB.
#define WS_Q     0      // 512
#define WS_QKS   512    // NH*DIM = 2048 (scale * Wk_h^T q_h), atomic-accumulated
#define WS_ATTN  2560   // 512
#define WS_S     3072   // NSLOT*NH = 64 softmax denominators
#define WS_XA    3136   // NSLOT*NH*DIM = 32768 weighted x-sum slots

// 128 blocks: one wave per output d; also zeros all atomic accumulators.
__global__ __launch_bounds__(256)
void k_qproj(const float* __restrict__ x, const float* __restrict__ ipw,
             const float* __restrict__ ipb, float* __restrict__ ws) {
  const int g = blockIdx.x * 256 + threadIdx.x;  // 0..32767
  ws[WS_XA + g] = 0.f;                            // exactly NSLOT*NH*DIM
  if (g < NSLOT * NH) ws[WS_S + g]   = 0.f;
  if (g < NH * DIM)   ws[WS_QKS + g] = 0.f;

  const int wave = threadIdx.x >> 6, lane = threadIdx.x & 63;
  const int d = blockIdx.x * 4 + wave;  // 0..511
  const float4 xa = *(const float4*)(x + lane * 8);
  const float4 xb = *(const float4*)(x + lane * 8 + 4);
  const float* wr = ipw + (size_t)d * DIM + lane * 8;
  const float4 wa = *(const float4*)wr;
  const float4 wb = *(const float4*)(wr + 4);
  float acc = wa.x*xa.x + wa.y*xa.y + wa.z*xa.z + wa.w*xa.w
            + wb.x*xb.x + wb.y*xb.y + wb.z*xb.z + wb.w*xb.w;
  #pragma unroll
  for (int off = 32; off; off >>= 1) acc += __shfl_xor(acc, off, 64);
  if (lane == 0) ws[WS_Q + d] = acc + ipb[d];
}

// 64 blocks x 4 waves = 256 waves: wave = (64-output chunk o) x (16-wide hd eighth).
// Coalesced 256B row-chunk loads; 8 atomicAdds per output address.
__global__ __launch_bounds__(256)
void k_qk(const float* __restrict__ ipw, float* __restrict__ ws) {
  const int wave = threadIdx.x >> 6, lane = threadIdx.x & 63;
  const int W  = blockIdx.x * 4 + wave;  // 0..255
  const int o  = W & 31;                 // output chunk (64 outputs)
  const int he = W >> 5;                 // hd eighth (16 rows)
  const int h  = o >> 3;
  const int col = o * 64 + lane;         // flat out index = h*512 + dp
  const int dp  = col & 511;
  const float* q = ws + WS_Q + h * HDIM + he * 16;
  const float* wbase = ipw + (size_t)(DIM + h * HDIM + he * 16) * DIM + dp;
  float acc = 0.f;
  #pragma unroll
  for (int i = 0; i < 16; ++i)
    acc += q[i] * wbase[(size_t)i * DIM];
  atomicAdd(ws + WS_QKS + col, acc * SCALE);
}

// Main pass: stream x; per row: 4 partial dots -> 4x4 lane-group transpose ->
// 4-stage butterfly -> one exp -> rotated-head accumulate. LDS 2-buffer
// combine; striped atomicAdd into xA/S slots.
__global__ __launch_bounds__(256, 4)
void k_main(const float* __restrict__ x, float* __restrict__ ws) {
  const int wave = threadIdx.x >> 6, lane = threadIdx.x & 63;
  const bool b1 = lane & 1, b2 = lane & 2;
  const int row0 = blockIdx.x * ROWS_PER_BLOCK + wave * ROWS_PER_WAVE;

  float qk[NH][8];
  #pragma unroll
  for (int h = 0; h < NH; ++h) {
    const float4 a = *(const float4*)(ws + WS_QKS + h * DIM + lane * 8);
    const float4 b = *(const float4*)(ws + WS_QKS + h * DIM + lane * 8 + 4);
    qk[h][0]=a.x; qk[h][1]=a.y; qk[h][2]=a.z; qk[h][3]=a.w;
    qk[h][4]=b.x; qk[h][5]=b.y; qk[h][6]=b.z; qk[h][7]=b.w;
  }

  float s = 0.f;          // denominator of head (lane&3), identical across its 16 lanes
  float xacc[NH][8];      // xacc[i] accumulates head (lane&3)^i
  #pragma unroll
  for (int i = 0; i < NH; ++i)
    #pragma unroll
    for (int j = 0; j < 8; ++j) xacc[i][j] = 0.f;

  const float* xp = x + (size_t)row0 * DIM + lane * 8;
  #pragma unroll
  for (int r = 0; r < ROWS_PER_WAVE; ++r) {
    const float* rp = xp + (size_t)r * DIM;
    const float4 a = *(const float4*)rp;
    const float4 b = *(const float4*)(rp + 4);
    const float xr[8] = {a.x,a.y,a.z,a.w,b.x,b.y,b.z,b.w};
    float d0=0.f,d1=0.f,d2=0.f,d3=0.f;
    #pragma unroll
    for (int j = 0; j < 8; ++j) {
      d0 += qk[0][j]*xr[j]; d1 += qk[1][j]*xr[j];
      d2 += qk[2][j]*xr[j]; d3 += qk[3][j]*xr[j];
    }
    // tier 1: 4x4 transpose-reduce within 4-lane groups -> lane holds head (l&3) group partial
    const float x01 = b1 ? d0 : d1;
    const float x23 = b1 ? d2 : d3;
    const float A = (b1 ? d1 : d0) + __shfl_xor(x01, 1, 64);
    const float B = (b1 ? d3 : d2) + __shfl_xor(x23, 1, 64);
    const float y = b2 ? A : B;
    float v = (b2 ? B : A) + __shfl_xor(y, 2, 64);
    // tier 2: butterfly over same-residue lanes -> full score of head (l&3)
    v += __shfl_xor(v, 4, 64);
    v += __shfl_xor(v, 8, 64);
    v += __shfl_xor(v, 16, 64);
    v += __shfl_xor(v, 32, 64);
    // one exp per row (per lane: its head)
    const float w0 = __expf(v);
    const float w1 = __shfl_xor(w0, 1, 64);   // head (l&3)^1
    const float w2 = __shfl_xor(w0, 2, 64);   // head (l&3)^2
    const float w3 = __shfl_xor(w0, 3, 64);   // head (l&3)^3
    s += w0;
    #pragma unroll
    for (int j = 0; j < 8; ++j) {
      xacc[0][j] += w0 * xr[j];
      xacc[1][j] += w1 * xr[j];
      xacc[2][j] += w2 * xr[j];
      xacc[3][j] += w3 * xr[j];
    }
  }

  // 2-buffer combine: waves 2,3 store; waves 0,1 add. 16.1 KB LDS.
  __shared__ float lds_xa[2][NH * DIM];
  __shared__ float lds_s[4][NH];
  const int hbase = lane & 3;
  if (wave >= 2) {
    #pragma unroll
    for (int i = 0; i < NH; ++i)
      #pragma unroll
      for (int j = 0; j < 8; ++j)
        lds_xa[wave - 2][((hbase ^ i) << 9) + lane * 8 + j] = xacc[i][j];
  }
  if (lane < NH) lds_s[wave][lane] = s;   // lane h holds head h's denominator
  __syncthreads();
  if (wave < 2) {
    #pragma unroll
    for (int i = 0; i < NH; ++i)
      #pragma unroll
      for (int j = 0; j < 8; ++j)
        lds_xa[wave][((hbase ^ i) << 9) + lane * 8 + j] += xacc[i][j];
  }
  __syncthreads();

  const int slot = blockIdx.x & (NSLOT - 1);
  if (threadIdx.x < NH) {
    const int h = threadIdx.x;
    atomicAdd(ws + WS_S + slot * NH + h,
              lds_s[0][h] + lds_s[1][h] + lds_s[2][h] + lds_s[3][h]);
  }
  #pragma unroll
  for (int j = 0; j < 8; ++j) {
    const int p = threadIdx.x + 256 * j;  // 0..2047, stride-1 across lanes
    atomicAdd(ws + WS_XA + slot * (NH * DIM) + p, lds_xa[0][p] + lds_xa[1][p]);
  }
}

// 128 blocks: one wave per output c. Sums the 16 xA/S slots inline.
__global__ __launch_bounds__(256)
void k_vproj(const float* __restrict__ ipw, const float* __restrict__ ipb,
             float* __restrict__ ws) {
  const int wave = threadIdx.x >> 6, lane = threadIdx.x & 63;
  const int c = blockIdx.x * 4 + wave;  // 0..511
  const int h = c >> 7;
  float xs[8] = {0.f,0.f,0.f,0.f,0.f,0.f,0.f,0.f};
  #pragma unroll
  for (int sl = 0; sl < NSLOT; ++sl) {
    const float* xv = ws + WS_XA + sl * (NH * DIM) + h * DIM + lane * 8;
    const float4 a = *(const float4*)xv;
    const float4 b = *(const float4*)(xv + 4);
    xs[0]+=a.x; xs[1]+=a.y; xs[2]+=a.z; xs[3]+=a.w;
    xs[4]+=b.x; xs[5]+=b.y; xs[6]+=b.z; xs[7]+=b.w;
  }
  float S = 0.f;
  #pragma unroll
  for (int sl = 0; sl < NSLOT; ++sl) S += ws[WS_S + sl * NH + h];

  const float* wr = ipw + (size_t)(2 * DIM + c) * DIM + lane * 8;
  const float4 wa = *(const float4*)wr;
  const float4 wb = *(const float4*)(wr + 4);
  float acc = wa.x*xs[0] + wa.y*xs[1] + wa.z*xs[2] + wa.w*xs[3]
            + wb.x*xs[4] + wb.y*xs[5] + wb.z*xs[6] + wb.w*xs[7];
  #pragma unroll
  for (int off = 32; off; off >>= 1) acc += __shfl_xor(acc, off, 64);
  if (lane == 0)
    ws[WS_ATTN + c] = acc / S + ipb[2 * DIM + c];
}

// 128 blocks: one wave per output i.
__global__ __launch_bounds__(256)
void k_oproj(const float* __restrict__ opw, const float* __restrict__ opb,
             const float* __restrict__ ws, float* __restrict__ out) {
  const int wave = threadIdx.x >> 6, lane = threadIdx.x & 63;
  const int i = blockIdx.x * 4 + wave;  // 0..511
  const float4 aa = *(const float4*)(ws + WS_ATTN + lane * 8);
  const float4 ab = *(const float4*)(ws + WS_ATTN + lane * 8 + 4);
  const float* wr = opw + (size_t)i * DIM + lane * 8;
  const float4 wa = *(const float4*)wr;
  const float4 wb = *(const float4*)(wr + 4);
  float acc = wa.x*aa.x + wa.y*aa.y + wa.z*aa.z + wa.w*aa.w
            + wb.x*ab.x + wb.y*ab.y + wb.z*ab.z + wb.w*ab.w;
  #pragma unroll
  for (int off = 32; off; off >>= 1) acc += __shfl_xor(acc, off, 64);
  if (lane == 0) out[i] = acc + opb[i];
}

extern "C" void kernel_launch(void* const* d_in, const int* in_sizes, int n_in,
                              void* d_out, int out_size, void* d_ws, size_t ws_size,
                              hipStream_t stream) {
  const float* x   = (const float*)d_in[0];
  const float* ipw = (const float*)d_in[1];
  const float* ipb = (const float*)d_in[2];
  const float* opw = (const float*)d_in[3];
  const float* opb = (const float*)d_in[4];
  float* out = (float*)d_out;
  float* ws  = (float*)d_ws;

  k_qproj<<<128, 256, 0, stream>>>(x, ipw, ipb, ws);
  k_qk   <<<64,  256, 0, stream>>>(ipw, ws);
  k_main <<<NB,  256, 0, stream>>>(x, ws);
  k_vproj<<<128, 256, 0, stream>>>(ipw, ipb, ws);
  k_oproj<<<128, 256, 0, stream>>>(opw, opb, ws, out);
}

// Round 9
// 118.022 us; speedup vs baseline: 1.3907x; 1.0611x over previous
//
#include <hip/hip_runtime.h>

// Single-query cross-attention, algebraically collapsed:
//   scores[h,l] = (scale*Wk_h^T q_h) . x[l]      (k-bias cancels in softmax)
//   out_attn[h] = Wv_h @ (sum_l softmax_w[l] * x[l]) + bv_h
// => one streaming pass over x (64 MB), memory-bound.
// R9: k_main ROWS_PER_WAVE 4->8 (NB 1024, 64KB/block), NSLOT 16->32
// (atomic depth 128->32); small kernels re-gridded to 1 wave/block spread
// across all CUs (qproj/vproj/oproj 512x64, qk 256x64).

#define DIM   512
#define NH    4
#define HDIM  128
#define SCALE 0.08838834764831845f  // 1/sqrt(128)

#define NB              1024
#define ROWS_PER_BLOCK  32
#define ROWS_PER_WAVE   8
#define NSLOT           32

// ws layout (float offsets). Total 68736 floats ~ 275 KB.
#define WS_Q     0      // 512
#define WS_QKS   512    // NH*DIM = 2048 (scale * Wk_h^T q_h), atomic-accumulated
#define WS_ATTN  2560   // 512
#define WS_S     3072   // NSLOT*NH = 128 softmax denominators
#define WS_XA    3200   // NSLOT*NH*DIM = 65536 weighted x-sum slots

// 512 blocks x 1 wave: one wave per output d; also zeros all accumulators.
__global__ __launch_bounds__(64)
void k_qproj(const float* __restrict__ x, const float* __restrict__ ipw,
             const float* __restrict__ ipb, float* __restrict__ ws) {
  const int g = blockIdx.x * 64 + threadIdx.x;  // 0..32767
  ws[WS_XA + g] = 0.f;
  ws[WS_XA + 32768 + g] = 0.f;                  // 65536 = NSLOT*NH*DIM total
  if (g < NSLOT * NH) ws[WS_S + g]   = 0.f;
  if (g < NH * DIM)   ws[WS_QKS + g] = 0.f;

  const int lane = threadIdx.x;
  const int d = blockIdx.x;  // 0..511
  const float4 xa = *(const float4*)(x + lane * 8);
  const float4 xb = *(const float4*)(x + lane * 8 + 4);
  const float* wr = ipw + (size_t)d * DIM + lane * 8;
  const float4 wa = *(const float4*)wr;
  const float4 wb = *(const float4*)(wr + 4);
  float acc = wa.x*xa.x + wa.y*xa.y + wa.z*xa.z + wa.w*xa.w
            + wb.x*xb.x + wb.y*xb.y + wb.z*xb.z + wb.w*xb.w;
  #pragma unroll
  for (int off = 32; off; off >>= 1) acc += __shfl_xor(acc, off, 64);
  if (lane == 0) ws[WS_Q + d] = acc + ipb[d];
}

// 256 blocks x 1 wave: wave = (64-output chunk o) x (16-wide hd eighth).
// Coalesced 256B row-chunk loads; 8 atomicAdds per output address.
__global__ __launch_bounds__(64)
void k_qk(const float* __restrict__ ipw, float* __restrict__ ws) {
  const int lane = threadIdx.x;
  const int W  = blockIdx.x;             // 0..255
  const int o  = W & 31;                 // output chunk (64 outputs)
  const int he = W >> 5;                 // hd eighth (16 rows)
  const int h  = o >> 3;
  const int col = o * 64 + lane;         // flat out index = h*512 + dp
  const int dp  = col & 511;
  const float* q = ws + WS_Q + h * HDIM + he * 16;
  const float* wbase = ipw + (size_t)(DIM + h * HDIM + he * 16) * DIM + dp;
  float acc = 0.f;
  #pragma unroll
  for (int i = 0; i < 16; ++i)
    acc += q[i] * wbase[(size_t)i * DIM];
  atomicAdd(ws + WS_QKS + col, acc * SCALE);
}

// Main pass: stream x; per row: 4 partial dots -> 4x4 lane-group transpose ->
// 4-stage butterfly -> one exp -> rotated-head accumulate. LDS 2-buffer
// combine; striped atomicAdd into xA/S slots.
__global__ __launch_bounds__(256, 4)
void k_main(const float* __restrict__ x, float* __restrict__ ws) {
  const int wave = threadIdx.x >> 6, lane = threadIdx.x & 63;
  const bool b1 = lane & 1, b2 = lane & 2;
  const int row0 = blockIdx.x * ROWS_PER_BLOCK + wave * ROWS_PER_WAVE;

  float qk[NH][8];
  #pragma unroll
  for (int h = 0; h < NH; ++h) {
    const float4 a = *(const float4*)(ws + WS_QKS + h * DIM + lane * 8);
    const float4 b = *(const float4*)(ws + WS_QKS + h * DIM + lane * 8 + 4);
    qk[h][0]=a.x; qk[h][1]=a.y; qk[h][2]=a.z; qk[h][3]=a.w;
    qk[h][4]=b.x; qk[h][5]=b.y; qk[h][6]=b.z; qk[h][7]=b.w;
  }

  float s = 0.f;          // denominator of head (lane&3), identical across its 16 lanes
  float xacc[NH][8];      // xacc[i] accumulates head (lane&3)^i
  #pragma unroll
  for (int i = 0; i < NH; ++i)
    #pragma unroll
    for (int j = 0; j < 8; ++j) xacc[i][j] = 0.f;

  const float* xp = x + (size_t)row0 * DIM + lane * 8;
  #pragma unroll
  for (int r = 0; r < ROWS_PER_WAVE; ++r) {
    const float* rp = xp + (size_t)r * DIM;
    const float4 a = *(const float4*)rp;
    const float4 b = *(const float4*)(rp + 4);
    const float xr[8] = {a.x,a.y,a.z,a.w,b.x,b.y,b.z,b.w};
    float d0=0.f,d1=0.f,d2=0.f,d3=0.f;
    #pragma unroll
    for (int j = 0; j < 8; ++j) {
      d0 += qk[0][j]*xr[j]; d1 += qk[1][j]*xr[j];
      d2 += qk[2][j]*xr[j]; d3 += qk[3][j]*xr[j];
    }
    // tier 1: 4x4 transpose-reduce within 4-lane groups -> lane holds head (l&3) group partial
    const float x01 = b1 ? d0 : d1;
    const float x23 = b1 ? d2 : d3;
    const float A = (b1 ? d1 : d0) + __shfl_xor(x01, 1, 64);
    const float B = (b1 ? d3 : d2) + __shfl_xor(x23, 1, 64);
    const float y = b2 ? A : B;
    float v = (b2 ? B : A) + __shfl_xor(y, 2, 64);
    // tier 2: butterfly over same-residue lanes -> full score of head (l&3)
    v += __shfl_xor(v, 4, 64);
    v += __shfl_xor(v, 8, 64);
    v += __shfl_xor(v, 16, 64);
    v += __shfl_xor(v, 32, 64);
    // one exp per row (per lane: its head)
    const float w0 = __expf(v);
    const float w1 = __shfl_xor(w0, 1, 64);   // head (l&3)^1
    const float w2 = __shfl_xor(w0, 2, 64);   // head (l&3)^2
    const float w3 = __shfl_xor(w0, 3, 64);   // head (l&3)^3
    s += w0;
    #pragma unroll
    for (int j = 0; j < 8; ++j) {
      xacc[0][j] += w0 * xr[j];
      xacc[1][j] += w1 * xr[j];
      xacc[2][j] += w2 * xr[j];
      xacc[3][j] += w3 * xr[j];
    }
  }

  // 2-buffer combine: waves 2,3 store; waves 0,1 add. 16.1 KB LDS.
  __shared__ float lds_xa[2][NH * DIM];
  __shared__ float lds_s[4][NH];
  const int hbase = lane & 3;
  if (wave >= 2) {
    #pragma unroll
    for (int i = 0; i < NH; ++i)
      #pragma unroll
      for (int j = 0; j < 8; ++j)
        lds_xa[wave - 2][((hbase ^ i) << 9) + lane * 8 + j] = xacc[i][j];
  }
  if (lane < NH) lds_s[wave][lane] = s;   // lane h holds head h's denominator
  __syncthreads();
  if (wave < 2) {
    #pragma unroll
    for (int i = 0; i < NH; ++i)
      #pragma unroll
      for (int j = 0; j < 8; ++j)
        lds_xa[wave][((hbase ^ i) << 9) + lane * 8 + j] += xacc[i][j];
  }
  __syncthreads();

  const int slot = blockIdx.x & (NSLOT - 1);
  if (threadIdx.x < NH) {
    const int h = threadIdx.x;
    atomicAdd(ws + WS_S + slot * NH + h,
              lds_s[0][h] + lds_s[1][h] + lds_s[2][h] + lds_s[3][h]);
  }
  #pragma unroll
  for (int j = 0; j < 8; ++j) {
    const int p = threadIdx.x + 256 * j;  // 0..2047, stride-1 across lanes
    atomicAdd(ws + WS_XA + slot * (NH * DIM) + p, lds_xa[0][p] + lds_xa[1][p]);
  }
}

// 512 blocks x 1 wave: one wave per output c. Sums the 32 xA/S slots inline
// (slot arrays are L2-resident: 4 heads x 32 slots x 2KB = 256KB unique).
__global__ __launch_bounds__(64)
void k_vproj(const float* __restrict__ ipw, const float* __restrict__ ipb,
             float* __restrict__ ws) {
  const int lane = threadIdx.x;
  const int c = blockIdx.x;  // 0..511
  const int h = c >> 7;
  float xs[8] = {0.f,0.f,0.f,0.f,0.f,0.f,0.f,0.f};
  #pragma unroll
  for (int sl = 0; sl < NSLOT; ++sl) {
    const float* xv = ws + WS_XA + sl * (NH * DIM) + h * DIM + lane * 8;
    const float4 a = *(const float4*)xv;
    const float4 b = *(const float4*)(xv + 4);
    xs[0]+=a.x; xs[1]+=a.y; xs[2]+=a.z; xs[3]+=a.w;
    xs[4]+=b.x; xs[5]+=b.y; xs[6]+=b.z; xs[7]+=b.w;
  }
  float S = 0.f;
  #pragma unroll
  for (int sl = 0; sl < NSLOT; ++sl) S += ws[WS_S + sl * NH + h];

  const float* wr = ipw + (size_t)(2 * DIM + c) * DIM + lane * 8;
  const float4 wa = *(const float4*)wr;
  const float4 wb = *(const float4*)(wr + 4);
  float acc = wa.x*xs[0] + wa.y*xs[1] + wa.z*xs[2] + wa.w*xs[3]
            + wb.x*xs[4] + wb.y*xs[5] + wb.z*xs[6] + wb.w*xs[7];
  #pragma unroll
  for (int off = 32; off; off >>= 1) acc += __shfl_xor(acc, off, 64);
  if (lane == 0)
    ws[WS_ATTN + c] = acc / S + ipb[2 * DIM + c];
}

// 512 blocks x 1 wave: one wave per output i.
__global__ __launch_bounds__(64)
void k_oproj(const float* __restrict__ opw, const float* __restrict__ opb,
             const float* __restrict__ ws, float* __restrict__ out) {
  const int lane = threadIdx.x;
  const int i = blockIdx.x;  // 0..511
  const float4 aa = *(const float4*)(ws + WS_ATTN + lane * 8);
  const float4 ab = *(const float4*)(ws + WS_ATTN + lane * 8 + 4);
  const float* wr = opw + (size_t)i * DIM + lane * 8;
  const float4 wa = *(const float4*)wr;
  const float4 wb = *(const float4*)(wr + 4);
  float acc = wa.x*aa.x + wa.y*aa.y + wa.z*aa.z + wa.w*aa.w
            + wb.x*ab.x + wb.y*ab.y + wb.z*ab.z + wb.w*ab.w;
  #pragma unroll
  for (int off = 32; off; off >>= 1) acc += __shfl_xor(acc, off, 64);
  if (lane == 0) out[i] = acc + opb[i];
}

extern "C" void kernel_launch(void* const* d_in, const int* in_sizes, int n_in,
                              void* d_out, int out_size, void* d_ws, size_t ws_size,
                              hipStream_t stream) {
  const float* x   = (const float*)d_in[0];
  const float* ipw = (const float*)d_in[1];
  const float* ipb = (const float*)d_in[2];
  const float* opw = (const float*)d_in[3];
  const float* opb = (const float*)d_in[4];
  float* out = (float*)d_out;
  float* ws  = (float*)d_ws;

  k_qproj<<<512, 64, 0, stream>>>(x, ipw, ipb, ws);
  k_qk   <<<256, 64, 0, stream>>>(ipw, ws);
  k_main <<<NB, 256, 0, stream>>>(x, ws);
  k_vproj<<<512, 64, 0, stream>>>(ipw, ipb, ws);
  k_oproj<<<512, 64, 0, stream>>>(opw, opb, ws, out);
}